// Round 6
// baseline (280.281 us; speedup 1.0000x reference)
//
#include <hip/hip_runtime.h>

#define NPTS 2048
#define NOVER 6144
#define STEP1 1536
#define STEP2 512
#define HW_TOT 262144

__device__ __forceinline__ float prelu_f(float x, float a) { return x >= 0.0f ? x : a * x; }

// coarse (128x128) bilinear coords for 512-output half-pixel sampling
__device__ __forceinline__ void coarse_coords(int h, int w, float& fy, float& fx,
                                              int& y0, int& y1, int& x0, int& x1) {
  float sy = (h + 0.5f) * 0.25f - 0.5f;
  float sx = (w + 0.5f) * 0.25f - 0.5f;
  float yf = floorf(sy), xf = floorf(sx);
  fy = sy - yf; fx = sx - xf;
  int yi = (int)yf, xi = (int)xf;
  y0 = min(127, max(0, yi)); y1 = min(127, max(0, yi + 1));
  x0 = min(127, max(0, xi)); x1 = min(127, max(0, xi + 1));
}

__device__ __forceinline__ float coarse_sample(const float* __restrict__ ch, float fy, float fx,
                                               int y0, int y1, int x0, int x1) {
  float v00 = ch[(y0 << 7) + x0];
  float v01 = ch[(y0 << 7) + x1];
  float v10 = ch[(y1 << 7) + x0];
  float v11 = ch[(y1 << 7) + x1];
  return (1.0f - fy) * ((1.0f - fx) * v00 + fx * v01) + fy * ((1.0f - fx) * v10 + fx * v11);
}

// merged: blocks 0..511 zero the f32 mask (2 MB); blocks 512..559 compute
// uncertainty keys (monotone u32 encoding of u in (0,1]). Both precede topk.
__global__ __launch_bounds__(256) void pr_uncfill_v9(uint4* __restrict__ mask4,
                                                     const float* __restrict__ coarse,
                                                     const int* __restrict__ ridx,
                                                     unsigned* __restrict__ keys) {
  const int bb = blockIdx.x;
  if (bb < 512) {
    mask4[bb * 256 + threadIdx.x] = make_uint4(0u, 0u, 0u, 0u);
    return;
  }
  int gid = (bb - 512) * 256 + threadIdx.x;
  if (gid >= 2 * NOVER) return;
  int b = gid / NOVER, i = gid - b * NOVER;
  int lin = ridx[i];
  int h = lin >> 9, w = lin & 511;
  float fy, fx; int y0, y1, x0, x1;
  coarse_coords(h, w, fy, fx, y0, y1, x0, x1);
  const float* cb = coarse + (((size_t)b * 3) << 14);
  float p0 = coarse_sample(cb, fy, fx, y0, y1, x0, x1);
  float p1 = coarse_sample(cb + (1 << 14), fy, fx, y0, y1, x0, x1);
  float p2 = coarse_sample(cb + (2 << 14), fy, fx, y0, y1, x0, x1);
  float m = fmaxf(p0, fmaxf(p1, p2));
  float e0 = expf(p0 - m), e1 = expf(p1 - m), e2 = expf(p2 - m);
  float s = e0 + e1 + e2;
  float q0 = e0 / s, q1 = e1 / s, q2 = e2 / s;
  float a0 = q0, a1 = q1, a2 = q2, tmp;
  if (a0 < a1) { tmp = a0; a0 = a1; a1 = tmp; }
  if (a1 < a2) { tmp = a1; a1 = a2; a2 = tmp; }
  if (a0 < a1) { tmp = a0; a0 = a1; a1 = tmp; }
  float u = 1.0f - (a0 - a1);   // strictly positive -> bit pattern is order-monotone
  keys[gid] = __float_as_uint(u);
}

// transpose w1 (256x259) -> wT1 (259x256), w2 (128x259) -> wT2 (259x128)
__global__ __launch_bounds__(256) void pr_wprep_v4(const float* __restrict__ w1,
                                                   const float* __restrict__ w2,
                                                   float* __restrict__ wT1,
                                                   float* __restrict__ wT2) {
  int gid = blockIdx.x * 256 + threadIdx.x;
  if (gid < 259 * 256) {
    int c = gid >> 8, o = gid & 255;
    wT1[c * 256 + o] = w1[o * 259 + c];
  } else {
    int g2 = gid - 259 * 256;
    if (g2 < 259 * 128) {
      int c = g2 >> 7, o = g2 & 127;
      wT2[c * 128 + o] = w2[o * 259 + c];
    }
  }
}

// One block per batch: exact radix-select top-1536 (val desc, idx asc tie-break),
// mask scatter, and bitmap-based ascending sort of the 2048 selected lins.
__global__ __launch_bounds__(1024) void pr_topk_v4(const unsigned* __restrict__ keys,
                                                   const int* __restrict__ ridx,
                                                   int* __restrict__ lin_sorted,
                                                   float* __restrict__ mask) {
  __shared__ unsigned kv[NOVER];            // 24 KB
  __shared__ unsigned bitmap[8192];         // 32 KB (262144 bits)
  __shared__ unsigned hist[256];
  __shared__ unsigned short tiebuf[NOVER];  // 12 KB (worst-case ties)
  __shared__ unsigned scanbuf[16];
  __shared__ unsigned selinfo[2];           // [0]=prefix/T, [1]=R
  __shared__ int tiecnt;
  const int b = blockIdx.x, t = threadIdx.x;
  const int lane = t & 63, wid = t >> 6;

  for (int i = t; i < NOVER; i += 1024) kv[i] = keys[b * NOVER + i];
  for (int i = t; i < 8192; i += 1024) bitmap[i] = 0u;
  if (t == 0) { selinfo[1] = STEP1; tiecnt = 0; }
  __syncthreads();

  // 4-pass radix select (descending): find exact threshold T and tie-rank r
  unsigned prefix = 0u;
  for (int pass = 0; pass < 4; ++pass) {
    const int shift = 24 - 8 * pass;
    const unsigned maskHi = (pass == 0) ? 0u : (0xFFFFFFFFu << (shift + 8));
    for (int i = t; i < 256; i += 1024) hist[i] = 0u;
    __syncthreads();
    for (int i = t; i < NOVER; i += 1024) {
      unsigned k = kv[i];
      if ((k & maskHi) == prefix) atomicAdd(&hist[(k >> shift) & 255u], 1u);
    }
    __syncthreads();
    if (t < 64) {  // one wave: suffix scan over 256 bins (4 bins/lane)
      unsigned h0 = hist[t * 4], h1 = hist[t * 4 + 1], h2 = hist[t * 4 + 2], h3 = hist[t * 4 + 3];
      unsigned q = h0 + h1 + h2 + h3;
      unsigned s = q;
      for (int off = 1; off < 64; off <<= 1) {
        unsigned n = __shfl_down(s, off);
        if (t + off < 64) s += n;
      }
      unsigned exq = s - q;                    // count in strictly-higher quads
      unsigned R = selinfo[1];                 // lockstep: all lanes read before any write
      unsigned se3 = exq, se2 = se3 + h3, se1 = se2 + h2, se0 = se1 + h1;
      if (se3 < R && R <= se3 + h3)      { selinfo[0] = prefix | ((unsigned)(t * 4 + 3) << shift); selinfo[1] = R - se3; }
      else if (se2 < R && R <= se2 + h2) { selinfo[0] = prefix | ((unsigned)(t * 4 + 2) << shift); selinfo[1] = R - se2; }
      else if (se1 < R && R <= se1 + h1) { selinfo[0] = prefix | ((unsigned)(t * 4 + 1) << shift); selinfo[1] = R - se1; }
      else if (se0 < R && R <= se0 + h0) { selinfo[0] = prefix | ((unsigned)(t * 4 + 0) << shift); selinfo[1] = R - se0; }
    }
    __syncthreads();
    prefix = selinfo[0];
  }
  const unsigned T = prefix;
  const int r = (int)selinfo[1];   // take r smallest-index items among key==T

  // selection pass: key > T definitely in; ties collected
  for (int i = t; i < NOVER; i += 1024) {
    unsigned k = kv[i];
    if (k > T) {
      int lin = ridx[i];
      mask[(size_t)b * HW_TOT + lin] = 1.0f;
      atomicOr(&bitmap[lin >> 5], 1u << (lin & 31));
    } else if (k == T) {
      int pos = atomicAdd(&tiecnt, 1);
      tiebuf[pos] = (unsigned short)i;
    }
  }
  // coverage points (last 512 of the permutation; disjoint from candidates)
  for (int i = t; i < STEP2; i += 1024) {
    int lin = ridx[HW_TOT - STEP2 + i];
    mask[(size_t)b * HW_TOT + lin] = 1.0f;
    atomicOr(&bitmap[lin >> 5], 1u << (lin & 31));
  }
  __syncthreads();
  const int m = tiecnt;
  for (int j = t; j < m; j += 1024) {
    int idx = tiebuf[j];
    int rank = 0;
    for (int jj = 0; jj < m; ++jj) rank += (tiebuf[jj] < idx) ? 1 : 0;
    if (rank < r) {
      int lin = ridx[idx];
      mask[(size_t)b * HW_TOT + lin] = 1.0f;
      atomicOr(&bitmap[lin >> 5], 1u << (lin & 31));
    }
  }
  __syncthreads();

  // bitmap -> ascending lin_sorted via popcount prefix scan (2048 set bits exactly)
  unsigned mySum = 0;
#pragma unroll
  for (int q = 0; q < 8; ++q) mySum += __popc(bitmap[t * 8 + q]);
  unsigned v = mySum;
  for (int off = 1; off < 64; off <<= 1) {
    unsigned n = __shfl_up(v, off);
    if (lane >= off) v += n;
  }
  if (lane == 63) scanbuf[wid] = v;
  __syncthreads();
  if (t == 0) {
    unsigned run = 0;
    for (int w16 = 0; w16 < 16; ++w16) { unsigned tmp = scanbuf[w16]; scanbuf[w16] = run; run += tmp; }
  }
  __syncthreads();
  unsigned pos = (v - mySum) + scanbuf[wid];
  for (int q = 0; q < 8; ++q) {
    unsigned word = bitmap[t * 8 + q];
    int basebit = (t * 8 + q) << 5;
    while (word) {
      int bit = __ffs(word) - 1;
      word &= word - 1;
      lin_sorted[b * NPTS + pos++] = basebit + bit;
    }
  }
}

// v9 gather: channel-major output; wave lanes = 64 CONSECUTIVE SORTED POINTS of
// one channel plane -> adjacent points share 64B rows of the plane (intra-wave
// cache-line sharing on all 4 corners) and writes are perfectly coalesced.
// fv[ch*4096 + s], cv[kk*4096 + s].
__global__ __launch_bounds__(256) void pr_gather_v9(const float* __restrict__ fine,
                                                    const float* __restrict__ coarse,
                                                    const int* __restrict__ lin_sorted,
                                                    float* __restrict__ fv,
                                                    float* __restrict__ cv) {
  const int tid = blockIdx.x * 256 + threadIdx.x;   // 0 .. 1060863
  if (tid < 1048576) {
    const int s = tid & 4095, ch = tid >> 12;
    const int bs = s >> 11;
    const int lin = lin_sorted[s];
    const int h = lin >> 9, w = lin & 511;
    float sy = (h + 0.5f) * 0.5f - 0.5f;
    float sx = (w + 0.5f) * 0.5f - 0.5f;
    float yf = floorf(sy), xf = floorf(sx);
    float fy = sy - yf, fx = sx - xf;
    int yi = (int)yf, xi = (int)xf;
    int y0 = min(255, max(0, yi)), y1 = min(255, max(0, yi + 1));
    int x0 = min(255, max(0, xi)), x1 = min(255, max(0, xi + 1));
    const float* base = fine + (((size_t)(bs * 256 + ch)) << 16);
    float v00 = base[(y0 << 8) + x0];
    float v01 = base[(y0 << 8) + x1];
    float v10 = base[(y1 << 8) + x0];
    float v11 = base[(y1 << 8) + x1];
    fv[tid] = (1.0f - fy) * ((1.0f - fx) * v00 + fx * v01)
            + fy * ((1.0f - fx) * v10 + fx * v11);
  } else {
    const int u = tid - 1048576;                    // 0 .. 12287
    const int s = u & 4095, kk = u >> 12;
    const int bs = s >> 11;
    const int lin = lin_sorted[s];
    const int h = lin >> 9, w = lin & 511;
    float fy, fx; int y0, y1, x0, x1;
    coarse_coords(h, w, fy, fx, y0, y1, x0, x1);
    cv[u] = coarse_sample(coarse + (((size_t)bs * 3 + kk) << 14), fy, fx, y0, y1, x0, x1);
  }
}

// v10 MLP = v9 + CORRECTED xs mapping: x[c] of point g is featflat[g*259+c]
// (the reference reshapes the flat [fine.ravel(), coarse.ravel()] concat by
// 259, so channel/point must be derived from the FLAT index j: ch=j&255,
// s=j>>8 for the fine region; (jj/3, jj%3) for the coarse region).
__global__ __launch_bounds__(512) void pr_mlpc_v10(const float* __restrict__ fv,
                                                   const float* __restrict__ cv,
                                                   const float* __restrict__ wT1,
                                                   const float* __restrict__ wT2,
                                                   const float* __restrict__ w3,
                                                   const float* __restrict__ pa,
                                                   float* __restrict__ out) {
  __shared__ __align__(16) float wbuf[2][8192];   // 64 KB weight chunk double-buffer
  __shared__ __align__(16) float xs[259][16];     // [c][p]  16.6 KB
  __shared__ __align__(16) float l1p[16][260];    // [p][c]  16.6 KB
  __shared__ __align__(16) float l2p[16][132];    // [p][c]   8.4 KB
  const int t = threadIdx.x;
  const int lane = t & 63, wid = t >> 6;
  const int g0 = blockIdx.x * 16;
  const float a = pa[0];

  // layer1 2D split: out-group (4 waves) x point-group (2 waves)
  const int ob1 = ((wid & 3) << 6) + ((lane & 15) << 2);   // out base: 4 outs
  const int pp1 = ((wid >> 2) << 3) + ((lane >> 4) << 1);  // point base: 2 pts
  const int ob2 = (t & 31) * 4;   // layer2: 4 outs (quad over 128)
  const int pt2 = t >> 5;         // layer2: point (0..15)

  // prefetch tail weight rows 256..258 for both layers
  float4 t1[3], t2[3];
#pragma unroll
  for (int i = 0; i < 3; ++i) {
    t1[i] = *(const float4*)&wT1[(256 + i) * 256 + ob1];
    t2[i] = *(const float4*)&wT2[(256 + i) * 128 + ob2];
  }
  // issue chunk 0 (wT1 rows 0..31) global loads; consumed after xs staging
  float4 st[4];
#pragma unroll
  for (int j = 0; j < 4; ++j) st[j] = *(const float4*)&wT1[(j * 512 + t) * 4];

  // xs stage: xs[c][p] = featflat[(g0+p)*259 + c], channel/point derived from
  // the flat index (featflat quirk). fv/cv tables are L2-resident.
  for (int task = t; task < 259 * 16; task += 512) {
    int c = task >> 4, p = task & 15;
    int j = (g0 + p) * 259 + c;
    float v;
    if (j < 1048576) {
      v = fv[(j & 255) * 4096 + (j >> 8)];
    } else {
      int jj = j - 1048576;
      int nsrc = jj / 3, kk = jj - nsrc * 3;
      v = cv[kk * 4096 + nsrc];
    }
    xs[c][p] = v;
  }
  // land chunk 0 into LDS buf0; barrier also publishes xs
#pragma unroll
  for (int j = 0; j < 4; ++j) *(float4*)&wbuf[0][(j * 512 + t) * 4] = st[j];
  __syncthreads();

  float acc1[4][2];
#pragma unroll
  for (int i = 0; i < 4; ++i) { acc1[i][0] = 0.0f; acc1[i][1] = 0.0f; }
  float acc2[4] = {0.0f, 0.0f, 0.0f, 0.0f};

  for (int k = 0; k < 12; ++k) {
    const int cur = k & 1;
    // issue next chunk's global loads (latency hidden under this chunk's compute)
    if (k < 11) {
      const float* src;
      if (k < 7)       src = wT1 + (k + 1) * 8192;   // L1 chunk k+1 (32 rows x 256)
      else if (k == 7) src = wT2;                    // L2 chunk 0   (64 rows x 128)
      else             src = wT2 + (k - 7) * 8192;   // L2 chunk k-7
#pragma unroll
      for (int j = 0; j < 4; ++j) st[j] = *(const float4*)&src[(j * 512 + t) * 4];
    }

    if (k < 8) {
      // layer1: this wave computes its 64-out x 8-pt tile of chunk k
      const float* w = wbuf[cur];
      const int c0 = k * 32;
#pragma unroll 8
      for (int cl = 0; cl < 32; ++cl) {
        const float4 wv = *(const float4*)&w[cl * 256 + ob1];   // 256B unique/wave, 4-lane broadcast
        const float2 xv = *(const float2*)&xs[c0 + cl][pp1];    // 4 distinct b64, 16-lane broadcast
        acc1[0][0] = fmaf(wv.x, xv.x, acc1[0][0]); acc1[0][1] = fmaf(wv.x, xv.y, acc1[0][1]);
        acc1[1][0] = fmaf(wv.y, xv.x, acc1[1][0]); acc1[1][1] = fmaf(wv.y, xv.y, acc1[1][1]);
        acc1[2][0] = fmaf(wv.z, xv.x, acc1[2][0]); acc1[2][1] = fmaf(wv.z, xv.y, acc1[2][1]);
        acc1[3][0] = fmaf(wv.w, xv.x, acc1[3][0]); acc1[3][1] = fmaf(wv.w, xv.y, acc1[3][1]);
      }
      if (k == 7) {
        // tail rows 256..258 from registers, prelu, transposed store to l1p
#pragma unroll
        for (int i = 0; i < 3; ++i) {
          const float2 xv = *(const float2*)&xs[256 + i][pp1];
          acc1[0][0] = fmaf(t1[i].x, xv.x, acc1[0][0]); acc1[0][1] = fmaf(t1[i].x, xv.y, acc1[0][1]);
          acc1[1][0] = fmaf(t1[i].y, xv.x, acc1[1][0]); acc1[1][1] = fmaf(t1[i].y, xv.y, acc1[1][1]);
          acc1[2][0] = fmaf(t1[i].z, xv.x, acc1[2][0]); acc1[2][1] = fmaf(t1[i].z, xv.y, acc1[2][1]);
          acc1[3][0] = fmaf(t1[i].w, xv.x, acc1[3][0]); acc1[3][1] = fmaf(t1[i].w, xv.y, acc1[3][1]);
        }
#pragma unroll
        for (int q = 0; q < 2; ++q) {
          float4 o;
          o.x = prelu_f(acc1[0][q], a);
          o.y = prelu_f(acc1[1][q], a);
          o.z = prelu_f(acc1[2][q], a);
          o.w = prelu_f(acc1[3][q], a);
          *(float4*)&l1p[pp1 + q][ob1] = o;
        }
      }
    } else {
      // layer2 compute on chunk k-8 (rows (k-8)*64 .. +63), K vectorized by 4
      const float* w = wbuf[cur];
      const int c0 = (k - 8) * 64;
#pragma unroll 4
      for (int cl = 0; cl < 64; cl += 4) {
        const float4 xv = *(const float4*)&l1p[pt2][c0 + cl];
        const float4 w0 = *(const float4*)&w[(cl + 0) * 128 + ob2];
        const float4 w1v = *(const float4*)&w[(cl + 1) * 128 + ob2];
        const float4 w2v = *(const float4*)&w[(cl + 2) * 128 + ob2];
        const float4 w3v = *(const float4*)&w[(cl + 3) * 128 + ob2];
        acc2[0] = fmaf(w0.x, xv.x, acc2[0]); acc2[1] = fmaf(w0.y, xv.x, acc2[1]);
        acc2[2] = fmaf(w0.z, xv.x, acc2[2]); acc2[3] = fmaf(w0.w, xv.x, acc2[3]);
        acc2[0] = fmaf(w1v.x, xv.y, acc2[0]); acc2[1] = fmaf(w1v.y, xv.y, acc2[1]);
        acc2[2] = fmaf(w1v.z, xv.y, acc2[2]); acc2[3] = fmaf(w1v.w, xv.y, acc2[3]);
        acc2[0] = fmaf(w2v.x, xv.z, acc2[0]); acc2[1] = fmaf(w2v.y, xv.z, acc2[1]);
        acc2[2] = fmaf(w2v.z, xv.z, acc2[2]); acc2[3] = fmaf(w2v.w, xv.z, acc2[3]);
        acc2[0] = fmaf(w3v.x, xv.w, acc2[0]); acc2[1] = fmaf(w3v.y, xv.w, acc2[1]);
        acc2[2] = fmaf(w3v.z, xv.w, acc2[2]); acc2[3] = fmaf(w3v.w, xv.w, acc2[3]);
      }
      if (k == 11) {
#pragma unroll
        for (int i = 0; i < 3; ++i) {
          const float x0 = xs[256 + i][pt2];
          acc2[0] = fmaf(t2[i].x, x0, acc2[0]); acc2[1] = fmaf(t2[i].y, x0, acc2[1]);
          acc2[2] = fmaf(t2[i].z, x0, acc2[2]); acc2[3] = fmaf(t2[i].w, x0, acc2[3]);
        }
        float4 o;
        o.x = prelu_f(acc2[0], a);
        o.y = prelu_f(acc2[1], a);
        o.z = prelu_f(acc2[2], a);
        o.w = prelu_f(acc2[3], a);
        *(float4*)&l2p[pt2][ob2] = o;
      }
    }

    // land next chunk into the other buffer (writes target buf nobody reads this iter)
    if (k < 11) {
#pragma unroll
      for (int j = 0; j < 4; ++j) *(float4*)&wbuf[cur ^ 1][(j * 512 + t) * 4] = st[j];
    }
    __syncthreads();
  }

  // layer 3: (128 + 3 tail) -> 3
  if (t < 48) {
    const int o3 = t % 3, p = t / 3;
    const float* wr = w3 + o3 * 131;
    float s = 0.0f;
#pragma unroll 4
    for (int c = 0; c < 128; ++c) s = fmaf(wr[c], l2p[p][c], s);
#pragma unroll
    for (int kk = 0; kk < 3; ++kk) s = fmaf(wr[128 + kk], xs[256 + kk][p], s);
    const int g = g0 + p;
    out[((g >> 11) * 3 + o3) * 2048 + (g & 2047)] = s;
  }
}

extern "C" void kernel_launch(void* const* d_in, const int* in_sizes, int n_in,
                              void* d_out, int out_size, void* d_ws, size_t ws_size,
                              hipStream_t stream) {
  const float* fine   = (const float*)d_in[0];
  const float* coarse = (const float*)d_in[1];
  const float* w1     = (const float*)d_in[2];
  const float* w2     = (const float*)d_in[3];
  const float* w3     = (const float*)d_in[4];
  const float* pa     = (const float*)d_in[5];
  const int*   ridx   = (const int*)d_in[6];

  float* out  = (float*)d_out;
  float* mask = out + 2 * 3 * 2048;            // f32 elem 12288, byte 49152 (16B aligned)

  char* ws = (char*)d_ws;
  int*      lin_sorted = (int*)ws;                    // @0        16384 B
  float*    wT1  = (float*)(ws + 16384);              // @16384    265216 B (259x256 f32)
  float*    wT2  = (float*)(ws + 281600);             // @281600   132608 B (259x128 f32)
  unsigned* keys = (unsigned*)(ws + 414208);          // @414208   49152 B (2x6144 u32)
  float*    fv   = (float*)(ws + 463360);             // @463360   4194304 B (256x4096 f32, ch-major)
  float*    cv   = (float*)(ws + 4657664);            // @4657664  49152 B (3x4096 f32)

  pr_uncfill_v9<<<560, 256, 0, stream>>>((uint4*)mask, coarse, ridx, keys);
  pr_wprep_v4<<<389, 256, 0, stream>>>(w1, w2, wT1, wT2);
  pr_topk_v4<<<2, 1024, 0, stream>>>(keys, ridx, lin_sorted, mask);
  pr_gather_v9<<<4144, 256, 0, stream>>>(fine, coarse, lin_sorted, fv, cv);
  pr_mlpc_v10<<<256, 512, 0, stream>>>(fv, cv, wT1, wT2, w3, pa, out);
}

// Round 7
// 262.771 us; speedup vs baseline: 1.0666x; 1.0666x over previous
//
#include <hip/hip_runtime.h>

#define NPTS 2048
#define NOVER 6144
#define STEP1 1536
#define STEP2 512
#define HW_TOT 262144

__device__ __forceinline__ float prelu_f(float x, float a) { return x >= 0.0f ? x : a * x; }

// coarse (128x128) bilinear coords for 512-output half-pixel sampling
__device__ __forceinline__ void coarse_coords(int h, int w, float& fy, float& fx,
                                              int& y0, int& y1, int& x0, int& x1) {
  float sy = (h + 0.5f) * 0.25f - 0.5f;
  float sx = (w + 0.5f) * 0.25f - 0.5f;
  float yf = floorf(sy), xf = floorf(sx);
  fy = sy - yf; fx = sx - xf;
  int yi = (int)yf, xi = (int)xf;
  y0 = min(127, max(0, yi)); y1 = min(127, max(0, yi + 1));
  x0 = min(127, max(0, xi)); x1 = min(127, max(0, xi + 1));
}

__device__ __forceinline__ float coarse_sample(const float* __restrict__ ch, float fy, float fx,
                                               int y0, int y1, int x0, int x1) {
  float v00 = ch[(y0 << 7) + x0];
  float v01 = ch[(y0 << 7) + x1];
  float v10 = ch[(y1 << 7) + x0];
  float v11 = ch[(y1 << 7) + x1];
  return (1.0f - fy) * ((1.0f - fx) * v00 + fx * v01) + fy * ((1.0f - fx) * v10 + fx * v11);
}

// v11 prep (one kernel, independent block ranges):
//   blocks   0..511: zero the f32 mask (2 MB)
//   blocks 512..559: uncertainty keys (monotone u32 encoding of u in (0,1])
//   blocks 560..948: transpose w1 -> wT1 (259x256), w2 -> wT2 (259x128)
__global__ __launch_bounds__(256) void pr_prep_v11(uint4* __restrict__ mask4,
                                                   const float* __restrict__ coarse,
                                                   const int* __restrict__ ridx,
                                                   unsigned* __restrict__ keys,
                                                   const float* __restrict__ w1,
                                                   const float* __restrict__ w2,
                                                   float* __restrict__ wT1,
                                                   float* __restrict__ wT2) {
  const int bb = blockIdx.x;
  if (bb < 512) {
    mask4[bb * 256 + threadIdx.x] = make_uint4(0u, 0u, 0u, 0u);
    return;
  }
  if (bb < 560) {
    int gid = (bb - 512) * 256 + threadIdx.x;
    if (gid >= 2 * NOVER) return;
    int b = gid / NOVER, i = gid - b * NOVER;
    int lin = ridx[i];
    int h = lin >> 9, w = lin & 511;
    float fy, fx; int y0, y1, x0, x1;
    coarse_coords(h, w, fy, fx, y0, y1, x0, x1);
    const float* cb = coarse + (((size_t)b * 3) << 14);
    float p0 = coarse_sample(cb, fy, fx, y0, y1, x0, x1);
    float p1 = coarse_sample(cb + (1 << 14), fy, fx, y0, y1, x0, x1);
    float p2 = coarse_sample(cb + (2 << 14), fy, fx, y0, y1, x0, x1);
    float m = fmaxf(p0, fmaxf(p1, p2));
    float e0 = expf(p0 - m), e1 = expf(p1 - m), e2 = expf(p2 - m);
    float s = e0 + e1 + e2;
    float q0 = e0 / s, q1 = e1 / s, q2 = e2 / s;
    float a0 = q0, a1 = q1, a2 = q2, tmp;
    if (a0 < a1) { tmp = a0; a0 = a1; a1 = tmp; }
    if (a1 < a2) { tmp = a1; a1 = a2; a2 = tmp; }
    if (a0 < a1) { tmp = a0; a0 = a1; a1 = tmp; }
    float u = 1.0f - (a0 - a1);   // strictly positive -> bit pattern is order-monotone
    keys[gid] = __float_as_uint(u);
    return;
  }
  int gid = (bb - 560) * 256 + threadIdx.x;
  if (gid < 259 * 256) {
    int c = gid >> 8, o = gid & 255;
    wT1[c * 256 + o] = w1[o * 259 + c];
  } else {
    int g2 = gid - 259 * 256;
    if (g2 < 259 * 128) {
      int c = g2 >> 7, o = g2 & 127;
      wT2[c * 128 + o] = w2[o * 259 + c];
    }
  }
}

// One block per batch: exact radix-select top-1536 (val desc, idx asc tie-break),
// mask scatter, and bitmap-based ascending sort of the 2048 selected lins.
__global__ __launch_bounds__(1024) void pr_topk_v4(const unsigned* __restrict__ keys,
                                                   const int* __restrict__ ridx,
                                                   int* __restrict__ lin_sorted,
                                                   float* __restrict__ mask) {
  __shared__ unsigned kv[NOVER];            // 24 KB
  __shared__ unsigned bitmap[8192];         // 32 KB (262144 bits)
  __shared__ unsigned hist[256];
  __shared__ unsigned short tiebuf[NOVER];  // 12 KB (worst-case ties)
  __shared__ unsigned scanbuf[16];
  __shared__ unsigned selinfo[2];           // [0]=prefix/T, [1]=R
  __shared__ int tiecnt;
  const int b = blockIdx.x, t = threadIdx.x;
  const int lane = t & 63, wid = t >> 6;

  for (int i = t; i < NOVER; i += 1024) kv[i] = keys[b * NOVER + i];
  for (int i = t; i < 8192; i += 1024) bitmap[i] = 0u;
  if (t == 0) { selinfo[1] = STEP1; tiecnt = 0; }
  __syncthreads();

  // 4-pass radix select (descending): find exact threshold T and tie-rank r
  unsigned prefix = 0u;
  for (int pass = 0; pass < 4; ++pass) {
    const int shift = 24 - 8 * pass;
    const unsigned maskHi = (pass == 0) ? 0u : (0xFFFFFFFFu << (shift + 8));
    for (int i = t; i < 256; i += 1024) hist[i] = 0u;
    __syncthreads();
    for (int i = t; i < NOVER; i += 1024) {
      unsigned k = kv[i];
      if ((k & maskHi) == prefix) atomicAdd(&hist[(k >> shift) & 255u], 1u);
    }
    __syncthreads();
    if (t < 64) {  // one wave: suffix scan over 256 bins (4 bins/lane)
      unsigned h0 = hist[t * 4], h1 = hist[t * 4 + 1], h2 = hist[t * 4 + 2], h3 = hist[t * 4 + 3];
      unsigned q = h0 + h1 + h2 + h3;
      unsigned s = q;
      for (int off = 1; off < 64; off <<= 1) {
        unsigned n = __shfl_down(s, off);
        if (t + off < 64) s += n;
      }
      unsigned exq = s - q;                    // count in strictly-higher quads
      unsigned R = selinfo[1];                 // lockstep: all lanes read before any write
      unsigned se3 = exq, se2 = se3 + h3, se1 = se2 + h2, se0 = se1 + h1;
      if (se3 < R && R <= se3 + h3)      { selinfo[0] = prefix | ((unsigned)(t * 4 + 3) << shift); selinfo[1] = R - se3; }
      else if (se2 < R && R <= se2 + h2) { selinfo[0] = prefix | ((unsigned)(t * 4 + 2) << shift); selinfo[1] = R - se2; }
      else if (se1 < R && R <= se1 + h1) { selinfo[0] = prefix | ((unsigned)(t * 4 + 1) << shift); selinfo[1] = R - se1; }
      else if (se0 < R && R <= se0 + h0) { selinfo[0] = prefix | ((unsigned)(t * 4 + 0) << shift); selinfo[1] = R - se0; }
    }
    __syncthreads();
    prefix = selinfo[0];
  }
  const unsigned T = prefix;
  const int r = (int)selinfo[1];   // take r smallest-index items among key==T

  // selection pass: key > T definitely in; ties collected
  for (int i = t; i < NOVER; i += 1024) {
    unsigned k = kv[i];
    if (k > T) {
      int lin = ridx[i];
      mask[(size_t)b * HW_TOT + lin] = 1.0f;
      atomicOr(&bitmap[lin >> 5], 1u << (lin & 31));
    } else if (k == T) {
      int pos = atomicAdd(&tiecnt, 1);
      tiebuf[pos] = (unsigned short)i;
    }
  }
  // coverage points (last 512 of the permutation; disjoint from candidates)
  for (int i = t; i < STEP2; i += 1024) {
    int lin = ridx[HW_TOT - STEP2 + i];
    mask[(size_t)b * HW_TOT + lin] = 1.0f;
    atomicOr(&bitmap[lin >> 5], 1u << (lin & 31));
  }
  __syncthreads();
  const int m = tiecnt;
  for (int j = t; j < m; j += 1024) {
    int idx = tiebuf[j];
    int rank = 0;
    for (int jj = 0; jj < m; ++jj) rank += (tiebuf[jj] < idx) ? 1 : 0;
    if (rank < r) {
      int lin = ridx[idx];
      mask[(size_t)b * HW_TOT + lin] = 1.0f;
      atomicOr(&bitmap[lin >> 5], 1u << (lin & 31));
    }
  }
  __syncthreads();

  // bitmap -> ascending lin_sorted via popcount prefix scan (2048 set bits exactly)
  unsigned mySum = 0;
#pragma unroll
  for (int q = 0; q < 8; ++q) mySum += __popc(bitmap[t * 8 + q]);
  unsigned v = mySum;
  for (int off = 1; off < 64; off <<= 1) {
    unsigned n = __shfl_up(v, off);
    if (lane >= off) v += n;
  }
  if (lane == 63) scanbuf[wid] = v;
  __syncthreads();
  if (t == 0) {
    unsigned run = 0;
    for (int w16 = 0; w16 < 16; ++w16) { unsigned tmp = scanbuf[w16]; scanbuf[w16] = run; run += tmp; }
  }
  __syncthreads();
  unsigned pos = (v - mySum) + scanbuf[wid];
  for (int q = 0; q < 8; ++q) {
    unsigned word = bitmap[t * 8 + q];
    int basebit = (t * 8 + q) << 5;
    while (word) {
      int bit = __ffs(word) - 1;
      word &= word - 1;
      lin_sorted[b * NPTS + pos++] = basebit + bit;
    }
  }
}

// v11 fused gather + MLP: 256 blocks x 512 threads, 16 pts/block.
// Gather phase: each block gathers ITS OWN 4144 featflat values directly into
// xs — 9-deep explicitly-unrolled issue/blend split so each thread has ~36
// scattered loads in flight (latency hidden by MLP-level parallelism: 8 waves
// x 512 threads/CU). No fv/cv table round-trip, no extra dispatch.
// MLP: v10's verified LDS double-buffered weight-chunk machinery, 2D wave
// split in layer 1.
__global__ __launch_bounds__(512) void pr_fused_v11(const float* __restrict__ fine,
                                                    const float* __restrict__ coarse,
                                                    const int* __restrict__ lin_sorted,
                                                    const float* __restrict__ wT1,
                                                    const float* __restrict__ wT2,
                                                    const float* __restrict__ w3,
                                                    const float* __restrict__ pa,
                                                    float* __restrict__ out) {
  __shared__ __align__(16) float wbuf[2][8192];   // 64 KB weight chunk double-buffer
  __shared__ __align__(16) float xs[259][16];     // [c][p]  16.6 KB
  __shared__ __align__(16) float l1p[16][260];    // [p][c]  16.6 KB
  __shared__ __align__(16) float l2p[16][132];    // [p][c]   8.4 KB
  const int t = threadIdx.x;
  const int lane = t & 63, wid = t >> 6;
  const int g0 = blockIdx.x * 16;
  const float a = pa[0];

  // layer1 2D split: out-group (4 waves) x point-group (2 waves)
  const int ob1 = ((wid & 3) << 6) + ((lane & 15) << 2);   // out base: 4 outs
  const int pp1 = ((wid >> 2) << 3) + ((lane >> 4) << 1);  // point base: 2 pts
  const int ob2 = (t & 31) * 4;   // layer2: 4 outs (quad over 128)
  const int pt2 = t >> 5;         // layer2: point (0..15)

  // prefetch tail weight rows 256..258 + issue chunk 0 weight loads first
  float4 t1[3], t2[3];
#pragma unroll
  for (int i = 0; i < 3; ++i) {
    t1[i] = *(const float4*)&wT1[(256 + i) * 256 + ob1];
    t2[i] = *(const float4*)&wT2[(256 + i) * 128 + ob2];
  }
  float4 st[4];
#pragma unroll
  for (int j = 0; j < 4; ++j) st[j] = *(const float4*)&wT1[(j * 512 + t) * 4];

  // ---- fused gather: issue phase (all 36 scattered loads in flight) ----
  // task -> (c = task>>4, p = task&15); x[c] of point g0+p = featflat[(g0+p)*259+c]
  float v00[9], v01[9], v10[9], v11[9], gfy[9], gfx[9];
#pragma unroll
  for (int it = 0; it < 9; ++it) {
    const int task = t + it * 512;
    if (task < 4144) {
      const int c = task >> 4, p = task & 15;
      const int j = (g0 + p) * 259 + c;
      if (j < 1048576) {
        const int nsrc = j >> 8, ch = j & 255;
        const int bs = nsrc >> 11;
        const int lin = lin_sorted[nsrc];
        const int h = lin >> 9, w = lin & 511;
        float sy = (h + 0.5f) * 0.5f - 0.5f;
        float sx = (w + 0.5f) * 0.5f - 0.5f;
        float yf = floorf(sy), xf = floorf(sx);
        gfy[it] = sy - yf; gfx[it] = sx - xf;
        int yi = (int)yf, xi = (int)xf;
        int y0 = min(255, max(0, yi)), y1 = min(255, max(0, yi + 1));
        int x0 = min(255, max(0, xi)), x1 = min(255, max(0, xi + 1));
        const float* base = fine + (((size_t)(bs * 256 + ch)) << 16);
        v00[it] = base[(y0 << 8) + x0];
        v01[it] = base[(y0 << 8) + x1];
        v10[it] = base[(y1 << 8) + x0];
        v11[it] = base[(y1 << 8) + x1];
      } else {
        const int jj = j - 1048576;
        const int nsrc = jj / 3, kk = jj - nsrc * 3;
        const int bs = nsrc >> 11;
        const int lin = lin_sorted[nsrc];
        const int h = lin >> 9, w = lin & 511;
        float fy, fx; int y0, y1, x0, x1;
        coarse_coords(h, w, fy, fx, y0, y1, x0, x1);
        gfy[it] = fy; gfx[it] = fx;
        const float* cb = coarse + (((size_t)bs * 3 + kk) << 14);
        v00[it] = cb[(y0 << 7) + x0];
        v01[it] = cb[(y0 << 7) + x1];
        v10[it] = cb[(y1 << 7) + x0];
        v11[it] = cb[(y1 << 7) + x1];
      }
    }
  }
  // ---- blend + store phase ----
#pragma unroll
  for (int it = 0; it < 9; ++it) {
    const int task = t + it * 512;
    if (task < 4144) {
      const int c = task >> 4, p = task & 15;
      const float fy = gfy[it], fx = gfx[it];
      xs[c][p] = (1.0f - fy) * ((1.0f - fx) * v00[it] + fx * v01[it])
               + fy * ((1.0f - fx) * v10[it] + fx * v11[it]);
    }
  }
  // land chunk 0 into LDS buf0; barrier also publishes xs
#pragma unroll
  for (int j = 0; j < 4; ++j) *(float4*)&wbuf[0][(j * 512 + t) * 4] = st[j];
  __syncthreads();

  float acc1[4][2];
#pragma unroll
  for (int i = 0; i < 4; ++i) { acc1[i][0] = 0.0f; acc1[i][1] = 0.0f; }
  float acc2[4] = {0.0f, 0.0f, 0.0f, 0.0f};

  for (int k = 0; k < 12; ++k) {
    const int cur = k & 1;
    // issue next chunk's global loads (latency hidden under this chunk's compute)
    if (k < 11) {
      const float* src;
      if (k < 7)       src = wT1 + (k + 1) * 8192;   // L1 chunk k+1 (32 rows x 256)
      else if (k == 7) src = wT2;                    // L2 chunk 0   (64 rows x 128)
      else             src = wT2 + (k - 7) * 8192;   // L2 chunk k-7
#pragma unroll
      for (int j = 0; j < 4; ++j) st[j] = *(const float4*)&src[(j * 512 + t) * 4];
    }

    if (k < 8) {
      // layer1: this wave computes its 64-out x 8-pt tile of chunk k
      const float* w = wbuf[cur];
      const int c0 = k * 32;
#pragma unroll 8
      for (int cl = 0; cl < 32; ++cl) {
        const float4 wv = *(const float4*)&w[cl * 256 + ob1];   // 256B unique/wave, 4-lane broadcast
        const float2 xv = *(const float2*)&xs[c0 + cl][pp1];    // 4 distinct b64, 16-lane broadcast
        acc1[0][0] = fmaf(wv.x, xv.x, acc1[0][0]); acc1[0][1] = fmaf(wv.x, xv.y, acc1[0][1]);
        acc1[1][0] = fmaf(wv.y, xv.x, acc1[1][0]); acc1[1][1] = fmaf(wv.y, xv.y, acc1[1][1]);
        acc1[2][0] = fmaf(wv.z, xv.x, acc1[2][0]); acc1[2][1] = fmaf(wv.z, xv.y, acc1[2][1]);
        acc1[3][0] = fmaf(wv.w, xv.x, acc1[3][0]); acc1[3][1] = fmaf(wv.w, xv.y, acc1[3][1]);
      }
      if (k == 7) {
        // tail rows 256..258 from registers, prelu, transposed store to l1p
#pragma unroll
        for (int i = 0; i < 3; ++i) {
          const float2 xv = *(const float2*)&xs[256 + i][pp1];
          acc1[0][0] = fmaf(t1[i].x, xv.x, acc1[0][0]); acc1[0][1] = fmaf(t1[i].x, xv.y, acc1[0][1]);
          acc1[1][0] = fmaf(t1[i].y, xv.x, acc1[1][0]); acc1[1][1] = fmaf(t1[i].y, xv.y, acc1[1][1]);
          acc1[2][0] = fmaf(t1[i].z, xv.x, acc1[2][0]); acc1[2][1] = fmaf(t1[i].z, xv.y, acc1[2][1]);
          acc1[3][0] = fmaf(t1[i].w, xv.x, acc1[3][0]); acc1[3][1] = fmaf(t1[i].w, xv.y, acc1[3][1]);
        }
#pragma unroll
        for (int q = 0; q < 2; ++q) {
          float4 o;
          o.x = prelu_f(acc1[0][q], a);
          o.y = prelu_f(acc1[1][q], a);
          o.z = prelu_f(acc1[2][q], a);
          o.w = prelu_f(acc1[3][q], a);
          *(float4*)&l1p[pp1 + q][ob1] = o;
        }
      }
    } else {
      // layer2 compute on chunk k-8 (rows (k-8)*64 .. +63), K vectorized by 4
      const float* w = wbuf[cur];
      const int c0 = (k - 8) * 64;
#pragma unroll 4
      for (int cl = 0; cl < 64; cl += 4) {
        const float4 xv = *(const float4*)&l1p[pt2][c0 + cl];
        const float4 w0 = *(const float4*)&w[(cl + 0) * 128 + ob2];
        const float4 w1v = *(const float4*)&w[(cl + 1) * 128 + ob2];
        const float4 w2v = *(const float4*)&w[(cl + 2) * 128 + ob2];
        const float4 w3v = *(const float4*)&w[(cl + 3) * 128 + ob2];
        acc2[0] = fmaf(w0.x, xv.x, acc2[0]); acc2[1] = fmaf(w0.y, xv.x, acc2[1]);
        acc2[2] = fmaf(w0.z, xv.x, acc2[2]); acc2[3] = fmaf(w0.w, xv.x, acc2[3]);
        acc2[0] = fmaf(w1v.x, xv.y, acc2[0]); acc2[1] = fmaf(w1v.y, xv.y, acc2[1]);
        acc2[2] = fmaf(w1v.z, xv.y, acc2[2]); acc2[3] = fmaf(w1v.w, xv.y, acc2[3]);
        acc2[0] = fmaf(w2v.x, xv.z, acc2[0]); acc2[1] = fmaf(w2v.y, xv.z, acc2[1]);
        acc2[2] = fmaf(w2v.z, xv.z, acc2[2]); acc2[3] = fmaf(w2v.w, xv.z, acc2[3]);
        acc2[0] = fmaf(w3v.x, xv.w, acc2[0]); acc2[1] = fmaf(w3v.y, xv.w, acc2[1]);
        acc2[2] = fmaf(w3v.z, xv.w, acc2[2]); acc2[3] = fmaf(w3v.w, xv.w, acc2[3]);
      }
      if (k == 11) {
#pragma unroll
        for (int i = 0; i < 3; ++i) {
          const float x0 = xs[256 + i][pt2];
          acc2[0] = fmaf(t2[i].x, x0, acc2[0]); acc2[1] = fmaf(t2[i].y, x0, acc2[1]);
          acc2[2] = fmaf(t2[i].z, x0, acc2[2]); acc2[3] = fmaf(t2[i].w, x0, acc2[3]);
        }
        float4 o;
        o.x = prelu_f(acc2[0], a);
        o.y = prelu_f(acc2[1], a);
        o.z = prelu_f(acc2[2], a);
        o.w = prelu_f(acc2[3], a);
        *(float4*)&l2p[pt2][ob2] = o;
      }
    }

    // land next chunk into the other buffer (writes target buf nobody reads this iter)
    if (k < 11) {
#pragma unroll
      for (int j = 0; j < 4; ++j) *(float4*)&wbuf[cur ^ 1][(j * 512 + t) * 4] = st[j];
    }
    __syncthreads();
  }

  // layer 3: (128 + 3 tail) -> 3
  if (t < 48) {
    const int o3 = t % 3, p = t / 3;
    const float* wr = w3 + o3 * 131;
    float s = 0.0f;
#pragma unroll 4
    for (int c = 0; c < 128; ++c) s = fmaf(wr[c], l2p[p][c], s);
#pragma unroll
    for (int kk = 0; kk < 3; ++kk) s = fmaf(wr[128 + kk], xs[256 + kk][p], s);
    const int g = g0 + p;
    out[((g >> 11) * 3 + o3) * 2048 + (g & 2047)] = s;
  }
}

extern "C" void kernel_launch(void* const* d_in, const int* in_sizes, int n_in,
                              void* d_out, int out_size, void* d_ws, size_t ws_size,
                              hipStream_t stream) {
  const float* fine   = (const float*)d_in[0];
  const float* coarse = (const float*)d_in[1];
  const float* w1     = (const float*)d_in[2];
  const float* w2     = (const float*)d_in[3];
  const float* w3     = (const float*)d_in[4];
  const float* pa     = (const float*)d_in[5];
  const int*   ridx   = (const int*)d_in[6];

  float* out  = (float*)d_out;
  float* mask = out + 2 * 3 * 2048;            // f32 elem 12288, byte 49152 (16B aligned)

  char* ws = (char*)d_ws;
  int*      lin_sorted = (int*)ws;                    // @0        16384 B
  float*    wT1  = (float*)(ws + 16384);              // @16384    265216 B (259x256 f32)
  float*    wT2  = (float*)(ws + 281600);             // @281600   132608 B (259x128 f32)
  unsigned* keys = (unsigned*)(ws + 414208);          // @414208   49152 B (2x6144 u32)

  pr_prep_v11<<<949, 256, 0, stream>>>((uint4*)mask, coarse, ridx, keys, w1, w2, wT1, wT2);
  pr_topk_v4<<<2, 1024, 0, stream>>>(keys, ridx, lin_sorted, mask);
  pr_fused_v11<<<256, 512, 0, stream>>>(fine, coarse, lin_sorted, wT1, wT2, w3, pa, out);
}